// Round 1
// 122.181 us; speedup vs baseline: 1.0581x; 1.0581x over previous
//
#include <hip/hip_runtime.h>
#include <cstddef>

// Problem constants
#define BB   8
#define CC   64
#define H1   128
#define W1   128
#define HW1  (H1*W1)
#define HS   60
#define WS   60
#define HO   129
#define WO   129
#define NPIX (HS*WS)        // 3600

// U: 36 planes of [BB][HW1], stored fp16
#define UPL  (BB*HW1)       // 131072 elements per t-plane

typedef _Float16 f16;

// ---------------------------------------------------------------------------
// inv-norm of x2 over channels: inv2[b,hw] = 1/||x2[b,:,hw]||
__global__ __launch_bounds__(256) void k_inv2(const float* __restrict__ x2,
                                              float* __restrict__ inv2) {
    int idx = blockIdx.x * 256 + threadIdx.x;   // 28800 (113 blocks)
    if (idx >= BB * NPIX) return;
    int b  = idx / NPIX;
    int hw = idx - b * NPIX;
    const float* p = x2 + (size_t)b * CC * NPIX + hw;
    float s = 0.f;
#pragma unroll
    for (int cc = 0; cc < CC; cc += 8) {
        float v0 = p[(cc+0)*NPIX], v1 = p[(cc+1)*NPIX];
        float v2 = p[(cc+2)*NPIX], v3 = p[(cc+3)*NPIX];
        float v4 = p[(cc+4)*NPIX], v5 = p[(cc+5)*NPIX];
        float v6 = p[(cc+6)*NPIX], v7 = p[(cc+7)*NPIX];
        s += v0*v0 + v1*v1 + v2*v2 + v3*v3 + v4*v4 + v5*v5 + v6*v6 + v7*v7;
    }
    inv2[idx] = 1.0f / sqrtf(s);
}

// ---------------------------------------------------------------------------
// fold 10x10 patch grid into 6x6 kernel per (b,c): S[b,c,dy*6+dx]
// ATOMIC-FREE: stage normalized plane in LDS, then 36 bins x 7 threads each
// sum a strided subset of the bin's 100 elements, small LDS reduce at the end.
__global__ __launch_bounds__(256) void k_fold(const float* __restrict__ x2,
                                              const float* __restrict__ inv2,
                                              float* __restrict__ S) {
    __shared__ __align__(16) float pl[NPIX];   // 14.4 KB
    __shared__ float red[256];
    int tid = threadIdx.x;
    int bc  = blockIdx.x;            // 512 = b*64+c
    int b   = bc >> 6;

    const float* px = x2 + (size_t)bc * NPIX;
    const float* pn = inv2 + (size_t)b * NPIX;

    // stage x2n plane (float4: 3600 = 900 quads, both bases 16B-aligned)
    const float4* px4 = (const float4*)px;
    const float4* pn4 = (const float4*)pn;
    float4* pl4 = (float4*)pl;
    for (int i = tid; i < NPIX / 4; i += 256) {
        float4 a = px4[i];
        float4 w = pn4[i];
        pl4[i] = make_float4(a.x * w.x, a.y * w.y, a.z * w.z, a.w * w.w);
    }
    __syncthreads();

    // bin t=(r,s): elements (r+6i, s+6j), i,j in [0,10). 7 partials per bin.
    float s = 0.f;
    if (tid < 252) {
        int bin = tid / 7, k = tid - bin * 7;
        int r = bin / 6, c6 = bin - r * 6;
        for (int e = k; e < 100; e += 7) {
            int i = e / 10, j = e - i * 10;
            s += pl[(r + 6 * i) * WS + (c6 + 6 * j)];
        }
    }
    red[tid] = s;
    __syncthreads();

    if (tid < 36) {
        const float* q = red + tid * 7;
        S[bc * 36 + tid] = q[0] + q[1] + q[2] + q[3] + q[4] + q[5] + q[6];
    }
}

// ---------------------------------------------------------------------------
// U[t][b][p] = inv1[b,p] * (1/3600) * sum_c x1[b,c,p] * S[b,c,t]
// inv1 computed in the same pass (x1 read exactly once, nontemporal).
// S is block-uniform -> scalar-cache loads. U stored as fp16.
// XCD swizzle: grid is 8 b x 64 chunks; remap so XCD k runs exactly b==k.
// U[b] then lives in XCD k's L2 for k_out (same swizzle there).
__global__ __launch_bounds__(256) void k_gemm(const float* __restrict__ x1,
                                              const float* __restrict__ S,
                                              f16* __restrict__ U) {
    int blk = (blockIdx.x & 7) * 64 + (blockIdx.x >> 3);  // bijective, 512%8==0
    int b = blk >> 6;
    int p = (blk & 63) * 256 + threadIdx.x;

    const float* xp = x1 + (size_t)b * CC * HW1 + p;
    const float* Sb = S + (size_t)b * (CC * 36);   // uniform base

    float acc[36];
#pragma unroll
    for (int t = 0; t < 36; ++t) acc[t] = 0.f;
    float s2 = 0.f;

    for (int cc = 0; cc < CC; cc += 8) {
        float v[8];
#pragma unroll
        for (int j = 0; j < 8; ++j)
            v[j] = __builtin_nontemporal_load(&xp[(size_t)(cc + j) * HW1]);
#pragma unroll
        for (int j = 0; j < 8; ++j) {
            const float* sj = Sb + (cc + j) * 36;   // uniform -> s_load
            float vv = v[j];
            s2 += vv * vv;
#pragma unroll
            for (int t = 0; t < 36; ++t) acc[t] += vv * sj[t];
        }
    }

    float inv = (1.0f / 3600.0f) / sqrtf(s2);
    f16* up = U + (size_t)b * HW1 + p;
#pragma unroll
    for (int t = 0; t < 36; ++t) up[(size_t)t * UPL] = (f16)(acc[t] * inv);
}

// ---------------------------------------------------------------------------
// Fused: out129 tile via 36-plane shifted gather of U (fp16), then bilinear
// antialias resize 129->128. One block per 16x16 output tile.
// Same XCD swizzle as k_gemm so U[b] reads hit the producing XCD's L2.
__global__ __launch_bounds__(256) void k_out(const f16* __restrict__ U,
                                             float* __restrict__ out) {
    __shared__ float m[20 * 21];
    int blk  = (blockIdx.x & 7) * 64 + (blockIdx.x >> 3); // bijective swizzle
    int b    = blk >> 6;
    int tile = blk & 63;
    int oy0 = (tile >> 3) * 16, ox0 = (tile & 7) * 16;
    int ry0 = oy0 - 1, rx0 = ox0 - 1;
    int tid = threadIdx.x;

    const f16* Ub = U + (size_t)b * HW1;

    // stage m[ly][lx] = out129[clamp(ry0+ly), clamp(rx0+lx)]
    for (int i = tid; i < 400; i += 256) {
        int ly = i / 20, lx = i - ly * 20;
        int jy = min(max(ry0 + ly, 0), 128);
        int jx = min(max(rx0 + lx, 0), 128);
        float s = 0.f;
#pragma unroll
        for (int t = 0; t < 36; ++t) {
            int dy = t / 6, dx = t - dy * 6;
            int py = jy - 3 + dy, px = jx - 3 + dx;
            if ((unsigned)py < 128u && (unsigned)px < 128u)
                s += (float)Ub[(size_t)t * UPL + py * W1 + px];
        }
        m[ly * 21 + lx] = s;
    }
    __syncthreads();

    const float inv_scale = 129.0f / 128.0f;
    const float ksc       = 128.0f / 129.0f;

    int oy = oy0 + (tid >> 4);
    int ox = ox0 + (tid & 15);

    float sy = (oy + 0.5f) * inv_scale - 0.5f;
    float sx = (ox + 0.5f) * inv_scale - 0.5f;
    int fy = (int)floorf(sy);
    int fx = (int)floorf(sx);

    float wy[4], wx[4];
    float sumy = 0.f, sumx = 0.f;
#pragma unroll
    for (int k = 0; k < 4; ++k) {
        int jy = fy - 1 + k;
        float w = 0.f;
        if (jy >= 0 && jy < HO) w = fmaxf(0.f, 1.0f - fabsf(sy - (float)jy) * ksc);
        wy[k] = w; sumy += w;
        int jx = fx - 1 + k;
        float w2 = 0.f;
        if (jx >= 0 && jx < WO) w2 = fmaxf(0.f, 1.0f - fabsf(sx - (float)jx) * ksc);
        wx[k] = w2; sumx += w2;
    }

    float r = 0.f;
#pragma unroll
    for (int ky = 0; ky < 4; ++ky) {
        if (wy[ky] == 0.f) continue;
        int ly = fy - 1 + ky - ry0;
        float rowv = 0.f;
#pragma unroll
        for (int kx = 0; kx < 4; ++kx) {
            if (wx[kx] == 0.f) continue;
            int lx = fx - 1 + kx - rx0;
            rowv += wx[kx] * m[ly * 21 + lx];
        }
        r += wy[ky] * rowv;
    }

    out[(size_t)b * HW1 + oy * W1 + ox] = r / (sumy * sumx);
}

// ---------------------------------------------------------------------------
extern "C" void kernel_launch(void* const* d_in, const int* in_sizes, int n_in,
                              void* d_out, int out_size, void* d_ws, size_t ws_size,
                              hipStream_t stream) {
    const float* x1 = (const float*)d_in[0];   // (8,64,128,128)
    const float* x2 = (const float*)d_in[1];   // (8,64,60,60)
    float* out = (float*)d_out;

    float* ws   = (float*)d_ws;
    float* inv2 = ws;                          // 28800 floats
    float* Sbuf = inv2 + BB * NPIX;            // 18432 floats
    f16*   U    = (f16*)(Sbuf + BB * CC * 36); // 36*131072 halves (9.4 MB)

    k_inv2<<<(BB * NPIX + 255) / 256, 256, 0, stream>>>(x2, inv2);
    k_fold<<<BB * CC, 256, 0, stream>>>(x2, inv2, Sbuf);
    k_gemm<<<BB * 64, 256, 0, stream>>>(x1, Sbuf, U);
    k_out <<<BB * 64, 256, 0, stream>>>(U, out);
}

// Round 2
// 118.968 us; speedup vs baseline: 1.0867x; 1.0270x over previous
//
#include <hip/hip_runtime.h>
#include <cstddef>

// Problem constants
#define BB   8
#define CC   64
#define H1   128
#define W1   128
#define HW1  (H1*W1)
#define HS   60
#define WS   60
#define HO   129
#define WO   129
#define NPIX (HS*WS)        // 3600

// U: 36 planes of [BB][HW1], stored fp16
#define UPL  (BB*HW1)       // 131072 elements per t-plane

typedef _Float16 f16;

// ---------------------------------------------------------------------------
// inv-norm of x2 over channels: inv2[b,hw] = 1/||x2[b,:,hw]||
// 4-way channel split (16 ch/thread) + LDS combine: 1800 waves instead of 113
// -> enough outstanding loads to cover HBM latency.
__global__ __launch_bounds__(256) void k_inv2(const float* __restrict__ x2,
                                              float* __restrict__ inv2) {
    __shared__ float red[256];
    int tid = threadIdx.x;
    int pix = blockIdx.x * 64 + (tid & 63);     // 450 blocks * 64 pix = 28800
    int q   = tid >> 6;                          // channel quarter 0..3

    int b  = pix / NPIX;
    int hw = pix - b * NPIX;
    const float* p = x2 + (size_t)b * CC * NPIX + (size_t)(q * 16) * NPIX + hw;

    float s = 0.f;
#pragma unroll
    for (int cc = 0; cc < 16; cc += 8) {
        float v0 = p[(cc+0)*NPIX], v1 = p[(cc+1)*NPIX];
        float v2 = p[(cc+2)*NPIX], v3 = p[(cc+3)*NPIX];
        float v4 = p[(cc+4)*NPIX], v5 = p[(cc+5)*NPIX];
        float v6 = p[(cc+6)*NPIX], v7 = p[(cc+7)*NPIX];
        s += v0*v0 + v1*v1 + v2*v2 + v3*v3 + v4*v4 + v5*v5 + v6*v6 + v7*v7;
    }
    red[tid] = s;
    __syncthreads();
    if (tid < 64) {
        float t = red[tid] + red[tid + 64] + red[tid + 128] + red[tid + 192];
        inv2[blockIdx.x * 64 + tid] = 1.0f / sqrtf(t);
    }
}

// ---------------------------------------------------------------------------
// fold 10x10 patch grid into 6x6 kernel per (b,c): S[b,c,dy*6+dx]
// ATOMIC-FREE: stage normalized plane in LDS, then 36 bins x 7 threads each
// sum a strided subset of the bin's 100 elements, small LDS reduce at the end.
__global__ __launch_bounds__(256) void k_fold(const float* __restrict__ x2,
                                              const float* __restrict__ inv2,
                                              float* __restrict__ S) {
    __shared__ __align__(16) float pl[NPIX];   // 14.4 KB
    __shared__ float red[256];
    int tid = threadIdx.x;
    int bc  = blockIdx.x;            // 512 = b*64+c
    int b   = bc >> 6;

    const float* px = x2 + (size_t)bc * NPIX;
    const float* pn = inv2 + (size_t)b * NPIX;

    // stage x2n plane (float4: 3600 = 900 quads, both bases 16B-aligned)
    const float4* px4 = (const float4*)px;
    const float4* pn4 = (const float4*)pn;
    float4* pl4 = (float4*)pl;
    for (int i = tid; i < NPIX / 4; i += 256) {
        float4 a = px4[i];
        float4 w = pn4[i];
        pl4[i] = make_float4(a.x * w.x, a.y * w.y, a.z * w.z, a.w * w.w);
    }
    __syncthreads();

    // bin t=(r,s): elements (r+6i, s+6j), i,j in [0,10). 7 partials per bin.
    float s = 0.f;
    if (tid < 252) {
        int bin = tid / 7, k = tid - bin * 7;
        int r = bin / 6, c6 = bin - r * 6;
        for (int e = k; e < 100; e += 7) {
            int i = e / 10, j = e - i * 10;
            s += pl[(r + 6 * i) * WS + (c6 + 6 * j)];
        }
    }
    red[tid] = s;
    __syncthreads();

    if (tid < 36) {
        const float* q = red + tid * 7;
        S[bc * 36 + tid] = q[0] + q[1] + q[2] + q[3] + q[4] + q[5] + q[6];
    }
}

// ---------------------------------------------------------------------------
// U[t][b][p] = inv1[b,p] * (1/3600) * sum_c x1[b,c,p] * S[b,c,t]
// inv1 computed in the same pass (x1 read exactly once, nontemporal).
// S is block-uniform -> scalar-cache loads. U stored as fp16.
// XCD swizzle: grid is 8 b x 64 chunks; remap so XCD k runs exactly b==k.
// U[b] then lives in XCD k's L2 for k_out (same swizzle there).
__global__ __launch_bounds__(256) void k_gemm(const float* __restrict__ x1,
                                              const float* __restrict__ S,
                                              f16* __restrict__ U) {
    int blk = (blockIdx.x & 7) * 64 + (blockIdx.x >> 3);  // bijective, 512%8==0
    int b = blk >> 6;
    int p = (blk & 63) * 256 + threadIdx.x;

    const float* xp = x1 + (size_t)b * CC * HW1 + p;
    const float* Sb = S + (size_t)b * (CC * 36);   // uniform base

    float acc[36];
#pragma unroll
    for (int t = 0; t < 36; ++t) acc[t] = 0.f;
    float s2 = 0.f;

#pragma unroll 2
    for (int cc = 0; cc < CC; cc += 8) {
        float v[8];
#pragma unroll
        for (int j = 0; j < 8; ++j)
            v[j] = __builtin_nontemporal_load(&xp[(size_t)(cc + j) * HW1]);
#pragma unroll
        for (int j = 0; j < 8; ++j) {
            const float* sj = Sb + (cc + j) * 36;   // uniform -> s_load
            float vv = v[j];
            s2 += vv * vv;
#pragma unroll
            for (int t = 0; t < 36; ++t) acc[t] += vv * sj[t];
        }
    }

    float inv = (1.0f / 3600.0f) / sqrtf(s2);
    f16* up = U + (size_t)b * HW1 + p;
#pragma unroll
    for (int t = 0; t < 36; ++t) up[(size_t)t * UPL] = (f16)(acc[t] * inv);
}

// ---------------------------------------------------------------------------
// Fused: out129 tile via 36-plane shifted gather of U (fp16), then bilinear
// antialias resize 129->128. One block per 16x16 output tile.
// Same XCD swizzle as k_gemm so U[b] reads hit the producing XCD's L2.
// Interior tiles (36/64) take a branch-free staging path.
__global__ __launch_bounds__(256) void k_out(const f16* __restrict__ U,
                                             float* __restrict__ out) {
    __shared__ float m[20 * 21];
    int blk  = (blockIdx.x & 7) * 64 + (blockIdx.x >> 3); // bijective swizzle
    int b    = blk >> 6;
    int tile = blk & 63;
    int oy0 = (tile >> 3) * 16, ox0 = (tile & 7) * 16;
    int ry0 = oy0 - 1, rx0 = ox0 - 1;
    int tid = threadIdx.x;

    const f16* Ub = U + (size_t)b * HW1;

    bool interior = (ry0 >= 3) && (ry0 + 19 <= 125) && (rx0 >= 3) && (rx0 + 19 <= 125);

    if (interior) {
        // no clamping, no bounds checks: all offsets compile-time off one base
        const f16* base = Ub + (size_t)(ry0 - 3) * W1 + (rx0 - 3);
        for (int i = tid; i < 400; i += 256) {
            int ly = i / 20, lx = i - ly * 20;
            const f16* pp = base + (size_t)ly * W1 + lx;
            float s = 0.f;
#pragma unroll
            for (int t = 0; t < 36; ++t) {
                int dy = t / 6, dx = t - dy * 6;
                s += (float)pp[(size_t)t * UPL + dy * W1 + dx];
            }
            m[ly * 21 + lx] = s;
        }
    } else {
        for (int i = tid; i < 400; i += 256) {
            int ly = i / 20, lx = i - ly * 20;
            int jy = min(max(ry0 + ly, 0), 128);
            int jx = min(max(rx0 + lx, 0), 128);
            float s = 0.f;
#pragma unroll
            for (int t = 0; t < 36; ++t) {
                int dy = t / 6, dx = t - dy * 6;
                int py = jy - 3 + dy, px = jx - 3 + dx;
                if ((unsigned)py < 128u && (unsigned)px < 128u)
                    s += (float)Ub[(size_t)t * UPL + py * W1 + px];
            }
            m[ly * 21 + lx] = s;
        }
    }
    __syncthreads();

    const float inv_scale = 129.0f / 128.0f;
    const float ksc       = 128.0f / 129.0f;

    int oy = oy0 + (tid >> 4);
    int ox = ox0 + (tid & 15);

    float sy = (oy + 0.5f) * inv_scale - 0.5f;
    float sx = (ox + 0.5f) * inv_scale - 0.5f;
    int fy = (int)floorf(sy);
    int fx = (int)floorf(sx);

    float wy[4], wx[4];
    float sumy = 0.f, sumx = 0.f;
#pragma unroll
    for (int k = 0; k < 4; ++k) {
        int jy = fy - 1 + k;
        float w = 0.f;
        if (jy >= 0 && jy < HO) w = fmaxf(0.f, 1.0f - fabsf(sy - (float)jy) * ksc);
        wy[k] = w; sumy += w;
        int jx = fx - 1 + k;
        float w2 = 0.f;
        if (jx >= 0 && jx < WO) w2 = fmaxf(0.f, 1.0f - fabsf(sx - (float)jx) * ksc);
        wx[k] = w2; sumx += w2;
    }

    float r = 0.f;
#pragma unroll
    for (int ky = 0; ky < 4; ++ky) {
        if (wy[ky] == 0.f) continue;
        int ly = fy - 1 + ky - ry0;
        float rowv = 0.f;
#pragma unroll
        for (int kx = 0; kx < 4; ++kx) {
            if (wx[kx] == 0.f) continue;
            int lx = fx - 1 + kx - rx0;
            rowv += wx[kx] * m[ly * 21 + lx];
        }
        r += wy[ky] * rowv;
    }

    out[(size_t)b * HW1 + oy * W1 + ox] = r / (sumy * sumx);
}

// ---------------------------------------------------------------------------
extern "C" void kernel_launch(void* const* d_in, const int* in_sizes, int n_in,
                              void* d_out, int out_size, void* d_ws, size_t ws_size,
                              hipStream_t stream) {
    const float* x1 = (const float*)d_in[0];   // (8,64,128,128)
    const float* x2 = (const float*)d_in[1];   // (8,64,60,60)
    float* out = (float*)d_out;

    float* ws   = (float*)d_ws;
    float* inv2 = ws;                          // 28800 floats
    float* Sbuf = inv2 + BB * NPIX;            // 18432 floats
    f16*   U    = (f16*)(Sbuf + BB * CC * 36); // 36*131072 halves (9.4 MB)

    k_inv2<<<BB * NPIX / 64, 256, 0, stream>>>(x2, inv2);
    k_fold<<<BB * CC, 256, 0, stream>>>(x2, inv2, Sbuf);
    k_gemm<<<BB * 64, 256, 0, stream>>>(x1, Sbuf, U);
    k_out <<<BB * 64, 256, 0, stream>>>(U, out);
}

// Round 4
// 114.463 us; speedup vs baseline: 1.1295x; 1.0394x over previous
//
#include <hip/hip_runtime.h>
#include <cstddef>
#include <cstdint>

// Problem constants
#define BB   8
#define CC   64
#define H1   128
#define W1   128
#define HW1  (H1*W1)
#define HS   60
#define WS   60
#define HO   129
#define WO   129
#define NPIX (HS*WS)        // 3600

// U: 36 planes of [BB][HW1], stored fp16
#define UPL  (BB*HW1)       // 131072 elements per t-plane

typedef _Float16 f16;
typedef __attribute__((ext_vector_type(2))) _Float16 h2;

#if __has_builtin(__builtin_amdgcn_fdot2)
#define FDOT2(a, b, c) __builtin_amdgcn_fdot2((a), (b), (c), false)
#else
#define FDOT2(a, b, c) ((c) + (float)(a)[0] * (float)(b)[0] + (float)(a)[1] * (float)(b)[1])
#endif

// cvt_pkrtz returns __fp16-vector; bit_cast to our _Float16-vector type.
static __device__ __forceinline__ h2 pack_h2(float lo, float hi) {
#if __has_builtin(__builtin_amdgcn_cvt_pkrtz)
    return __builtin_bit_cast(h2, __builtin_amdgcn_cvt_pkrtz(lo, hi));
#else
    h2 r; r[0] = (f16)lo; r[1] = (f16)hi; return r;
#endif
}

// ---------------------------------------------------------------------------
// inv-norm of x2 over channels: inv2[b,hw] = 1/||x2[b,:,hw]||
// 4-way channel split (16 ch/thread) + LDS combine: 1800 waves for latency.
__global__ __launch_bounds__(256) void k_inv2(const float* __restrict__ x2,
                                              float* __restrict__ inv2) {
    __shared__ float red[256];
    int tid = threadIdx.x;
    int pix = blockIdx.x * 64 + (tid & 63);     // 450 blocks * 64 pix = 28800
    int q   = tid >> 6;                          // channel quarter 0..3

    int b  = pix / NPIX;
    int hw = pix - b * NPIX;
    const float* p = x2 + (size_t)b * CC * NPIX + (size_t)(q * 16) * NPIX + hw;

    float s = 0.f;
#pragma unroll
    for (int cc = 0; cc < 16; cc += 8) {
        float v0 = p[(cc+0)*NPIX], v1 = p[(cc+1)*NPIX];
        float v2 = p[(cc+2)*NPIX], v3 = p[(cc+3)*NPIX];
        float v4 = p[(cc+4)*NPIX], v5 = p[(cc+5)*NPIX];
        float v6 = p[(cc+6)*NPIX], v7 = p[(cc+7)*NPIX];
        s += v0*v0 + v1*v1 + v2*v2 + v3*v3 + v4*v4 + v5*v5 + v6*v6 + v7*v7;
    }
    red[tid] = s;
    __syncthreads();
    if (tid < 64) {
        float t = red[tid] + red[tid + 64] + red[tid + 128] + red[tid + 192];
        inv2[blockIdx.x * 64 + tid] = 1.0f / sqrtf(t);
    }
}

// ---------------------------------------------------------------------------
// fold 10x10 patch grid into 6x6 kernel per (b,c).
// Output: Sh packed fp16, channel-pair interleaved:
//   Sh[(((b*32 + c/2)*36) + t)*2 + (c&1)] = S[b,c,t]
// so k_gemm reads one dword = {S[2cp,t], S[2cp+1,t]} for v_dot2_f32_f16.
__global__ __launch_bounds__(256) void k_fold(const float* __restrict__ x2,
                                              const float* __restrict__ inv2,
                                              f16* __restrict__ Sh) {
    __shared__ __align__(16) float pl[NPIX];   // 14.4 KB
    __shared__ float red[256];
    int tid = threadIdx.x;
    int bc  = blockIdx.x;            // 512 = b*64+c
    int b   = bc >> 6;
    int c   = bc & 63;

    const float* px = x2 + (size_t)bc * NPIX;
    const float* pn = inv2 + (size_t)b * NPIX;

    // stage x2n plane (float4: 3600 = 900 quads, both bases 16B-aligned)
    const float4* px4 = (const float4*)px;
    const float4* pn4 = (const float4*)pn;
    float4* pl4 = (float4*)pl;
    for (int i = tid; i < NPIX / 4; i += 256) {
        float4 a = px4[i];
        float4 w = pn4[i];
        pl4[i] = make_float4(a.x * w.x, a.y * w.y, a.z * w.z, a.w * w.w);
    }
    __syncthreads();

    // bin t=(r,s): elements (r+6i, s+6j), i,j in [0,10). 7 partials per bin.
    float s = 0.f;
    if (tid < 252) {
        int bin = tid / 7, k = tid - bin * 7;
        int r = bin / 6, c6 = bin - r * 6;
        for (int e = k; e < 100; e += 7) {
            int i = e / 10, j = e - i * 10;
            s += pl[(r + 6 * i) * WS + (c6 + 6 * j)];
        }
    }
    red[tid] = s;
    __syncthreads();

    if (tid < 36) {
        const float* q = red + tid * 7;
        float bin = q[0] + q[1] + q[2] + q[3] + q[4] + q[5] + q[6];
        Sh[(((size_t)b * 32 + (c >> 1)) * 36 + tid) * 2 + (c & 1)] = (f16)bin;
    }
}

// ---------------------------------------------------------------------------
// U[t][b][p] = inv1[b,p] * (1/3600) * sum_c x1[b,c,p] * S[b,c,t]
// Inner product via v_dot2_f32_f16: fp16 channel-pairs, fp32 accumulate.
// inv1 (s2) accumulated from the fp32 loads -> exact normalization.
// S dwords are block-uniform -> scalar-cache loads. U stored as fp16.
// XCD swizzle: XCD k runs exactly b==k; U[b] stays in that XCD's L2 for k_out.
__global__ __launch_bounds__(256) void k_gemm(const float* __restrict__ x1,
                                              const f16* __restrict__ Sh,
                                              f16* __restrict__ U) {
    int blk = (blockIdx.x & 7) * 64 + (blockIdx.x >> 3);  // bijective, 512%8==0
    int b = blk >> 6;
    int p = (blk & 63) * 256 + threadIdx.x;

    const float* xp = x1 + (size_t)b * CC * HW1 + p;
    const uint32_t* Sw = (const uint32_t*)Sh + (size_t)b * (32 * 36); // uniform

    float acc[36];
#pragma unroll
    for (int t = 0; t < 36; ++t) acc[t] = 0.f;
    float s2 = 0.f;

#pragma unroll 2
    for (int cc = 0; cc < CC; cc += 8) {
        float v[8];
#pragma unroll
        for (int j = 0; j < 8; ++j)
            v[j] = __builtin_nontemporal_load(&xp[(size_t)(cc + j) * HW1]);
        h2 a[4];
#pragma unroll
        for (int q = 0; q < 4; ++q) {
            a[q] = pack_h2(v[2*q], v[2*q+1]);
            s2 += v[2*q] * v[2*q] + v[2*q+1] * v[2*q+1];
        }
#pragma unroll
        for (int q = 0; q < 4; ++q) {
            const uint32_t* sq = Sw + (size_t)(cc / 2 + q) * 36;  // uniform
#pragma unroll
            for (int t = 0; t < 36; ++t) {
                h2 sv = __builtin_bit_cast(h2, sq[t]);
                acc[t] = FDOT2(a[q], sv, acc[t]);
            }
        }
    }

    float inv = (1.0f / 3600.0f) / sqrtf(s2);
    f16* up = U + (size_t)b * HW1 + p;
#pragma unroll
    for (int t = 0; t < 36; ++t) up[(size_t)t * UPL] = (f16)(acc[t] * inv);
}

// ---------------------------------------------------------------------------
// Fused: out129 tile via 36-plane shifted gather of U (fp16), then bilinear
// antialias resize 129->128. One block per 16x16 output tile.
// Same XCD swizzle as k_gemm so U[b] reads hit the producing XCD's L2.
// Interior tiles (36/64) take a branch-free staging path.
__global__ __launch_bounds__(256) void k_out(const f16* __restrict__ U,
                                             float* __restrict__ out) {
    __shared__ float m[20 * 21];
    int blk  = (blockIdx.x & 7) * 64 + (blockIdx.x >> 3); // bijective swizzle
    int b    = blk >> 6;
    int tile = blk & 63;
    int oy0 = (tile >> 3) * 16, ox0 = (tile & 7) * 16;
    int ry0 = oy0 - 1, rx0 = ox0 - 1;
    int tid = threadIdx.x;

    const f16* Ub = U + (size_t)b * HW1;

    bool interior = (ry0 >= 3) && (ry0 + 19 <= 125) && (rx0 >= 3) && (rx0 + 19 <= 125);

    if (interior) {
        // no clamping, no bounds checks: all offsets compile-time off one base
        const f16* base = Ub + (size_t)(ry0 - 3) * W1 + (rx0 - 3);
        for (int i = tid; i < 400; i += 256) {
            int ly = i / 20, lx = i - ly * 20;
            const f16* pp = base + (size_t)ly * W1 + lx;
            float s = 0.f;
#pragma unroll
            for (int t = 0; t < 36; ++t) {
                int dy = t / 6, dx = t - dy * 6;
                s += (float)pp[(size_t)t * UPL + dy * W1 + dx];
            }
            m[ly * 21 + lx] = s;
        }
    } else {
        for (int i = tid; i < 400; i += 256) {
            int ly = i / 20, lx = i - ly * 20;
            int jy = min(max(ry0 + ly, 0), 128);
            int jx = min(max(rx0 + lx, 0), 128);
            float s = 0.f;
#pragma unroll
            for (int t = 0; t < 36; ++t) {
                int dy = t / 6, dx = t - dy * 6;
                int py = jy - 3 + dy, px = jx - 3 + dx;
                if ((unsigned)py < 128u && (unsigned)px < 128u)
                    s += (float)Ub[(size_t)t * UPL + py * W1 + px];
            }
            m[ly * 21 + lx] = s;
        }
    }
    __syncthreads();

    const float inv_scale = 129.0f / 128.0f;
    const float ksc       = 128.0f / 129.0f;

    int oy = oy0 + (tid >> 4);
    int ox = ox0 + (tid & 15);

    float sy = (oy + 0.5f) * inv_scale - 0.5f;
    float sx = (ox + 0.5f) * inv_scale - 0.5f;
    int fy = (int)floorf(sy);
    int fx = (int)floorf(sx);

    float wy[4], wx[4];
    float sumy = 0.f, sumx = 0.f;
#pragma unroll
    for (int k = 0; k < 4; ++k) {
        int jy = fy - 1 + k;
        float w = 0.f;
        if (jy >= 0 && jy < HO) w = fmaxf(0.f, 1.0f - fabsf(sy - (float)jy) * ksc);
        wy[k] = w; sumy += w;
        int jx = fx - 1 + k;
        float w2 = 0.f;
        if (jx >= 0 && jx < WO) w2 = fmaxf(0.f, 1.0f - fabsf(sx - (float)jx) * ksc);
        wx[k] = w2; sumx += w2;
    }

    float r = 0.f;
#pragma unroll
    for (int ky = 0; ky < 4; ++ky) {
        if (wy[ky] == 0.f) continue;
        int ly = fy - 1 + ky - ry0;
        float rowv = 0.f;
#pragma unroll
        for (int kx = 0; kx < 4; ++kx) {
            if (wx[kx] == 0.f) continue;
            int lx = fx - 1 + kx - rx0;
            rowv += wx[kx] * m[ly * 21 + lx];
        }
        r += wy[ky] * rowv;
    }

    out[(size_t)b * HW1 + oy * W1 + ox] = r / (sumy * sumx);
}

// ---------------------------------------------------------------------------
extern "C" void kernel_launch(void* const* d_in, const int* in_sizes, int n_in,
                              void* d_out, int out_size, void* d_ws, size_t ws_size,
                              hipStream_t stream) {
    const float* x1 = (const float*)d_in[0];   // (8,64,128,128)
    const float* x2 = (const float*)d_in[1];   // (8,64,60,60)
    float* out = (float*)d_out;

    float* ws   = (float*)d_ws;
    float* inv2 = ws;                           // 28800 floats
    f16*   Sh   = (f16*)(inv2 + BB * NPIX);     // 8*64*36 f16 = 36864 B
    f16*   U    = (f16*)((char*)Sh + (size_t)BB * CC * 36 * sizeof(f16));

    k_inv2<<<BB * NPIX / 64, 256, 0, stream>>>(x2, inv2);
    k_fold<<<BB * CC, 256, 0, stream>>>(x2, inv2, Sh);
    k_gemm<<<BB * 64, 256, 0, stream>>>(x1, Sh, U);
    k_out <<<BB * 64, 256, 0, stream>>>(U, out);
}